// Round 1
// baseline (697.134 us; speedup 1.0000x reference)
//
#include <hip/hip_runtime.h>
#include <hip/hip_bf16.h>

#define B_ 4
#define C_ 256
#define N_ 4096

typedef unsigned short u16;
typedef __attribute__((ext_vector_type(8))) short bf16x8;
typedef __attribute__((ext_vector_type(4))) float f32x4;

static __device__ __forceinline__ u16 f2bf(float f) {
    unsigned u = __float_as_uint(f);
    unsigned r = (u + 0x7FFFu + ((u >> 16) & 1u)) >> 16;
    return (u16)r;
}

static __device__ __forceinline__ f32x4 mfma16(bf16x8 a, bf16x8 b, f32x4 c) {
    return __builtin_amdgcn_mfma_f32_16x16x32_bf16(a, b, c, 0, 0, 0);
}

// ---------------- kernel 1: weights f32 -> bf16 ----------------
__global__ void wconv_kernel(const float* __restrict__ wq, const float* __restrict__ wk,
                             const float* __restrict__ wv,
                             u16* __restrict__ wqb, u16* __restrict__ wkb, u16* __restrict__ wvb) {
    int i = blockIdx.x * blockDim.x + threadIdx.x;   // grid covers C_*C_
    wqb[i] = f2bf(wq[i]);
    wkb[i] = f2bf(wk[i]);
    wvb[i] = f2bf(wv[i]);
}

// ---------------- kernel 2: pose [B,C,N] f32 -> poseT [B,N,C] bf16 ----------------
__global__ void transpose_kernel(const float* __restrict__ pose, u16* __restrict__ poseT) {
    __shared__ float tile[64][65];
    int bid = blockIdx.x;              // B * 4 * 64 = 1024
    int b = bid >> 8;
    int rem = bid & 255;
    int ct = rem >> 6;                 // c-tile 0..3
    int nt = rem & 63;                 // n-tile 0..63
    int c0 = ct * 64, n0 = nt * 64;
    int tid = threadIdx.x;
    int lo = tid & 63, hi = tid >> 6;  // hi 0..3
#pragma unroll
    for (int r = 0; r < 16; ++r) {
        int cc = r * 4 + hi;
        tile[cc][lo] = pose[(size_t)(b * C_ + c0 + cc) * N_ + n0 + lo];
    }
    __syncthreads();
#pragma unroll
    for (int r = 0; r < 16; ++r) {
        int nn = r * 4 + hi;
        poseT[(size_t)(b * N_ + n0 + nn) * C_ + c0 + lo] = f2bf(tile[lo][nn]);
    }
}

// ---------------- kernel 3: projections ----------------
// Qm,Km: [B][N][C] bf16 ; Vm: [B][C][N] bf16
__global__ __launch_bounds__(256) void proj_kernel(
    const u16* __restrict__ poseT,
    const u16* __restrict__ wqb, const float* __restrict__ bq,
    const u16* __restrict__ wkb, const float* __restrict__ bk,
    const u16* __restrict__ wvb, const float* __restrict__ bv,
    u16* __restrict__ Qm, u16* __restrict__ Km, u16* __restrict__ Vm)
{
    int bid = blockIdx.x;              // B * N/64 = 256
    int b = bid >> 6;
    int n0 = (bid & 63) * 64;
    int lane = threadIdx.x & 63;
    int wav = threadIdx.x >> 6;        // 0..3
    int l15 = lane & 15, lg = lane >> 4;

    // ---- Q and K: out[n][d], wave owns 16 n-rows ----
    int nrow = n0 + wav * 16;
    const u16* arow = poseT + (size_t)(b * N_ + nrow + l15) * C_;
    bf16x8 afr[8];
#pragma unroll
    for (int kc = 0; kc < 8; ++kc)
        afr[kc] = *(const bf16x8*)(arow + kc * 32 + lg * 8);

    for (int qk = 0; qk < 2; ++qk) {
        const u16* wb = qk ? wkb : wqb;
        const float* bias = qk ? bk : bq;
        u16* outm = qk ? Km : Qm;
#pragma unroll
        for (int ct = 0; ct < 16; ++ct) {
            f32x4 acc = {0.f, 0.f, 0.f, 0.f};
            const u16* brow = wb + (size_t)(ct * 16 + l15) * C_;
#pragma unroll
            for (int kc = 0; kc < 8; ++kc) {
                bf16x8 bfr = *(const bf16x8*)(brow + kc * 32 + lg * 8);
                acc = mfma16(afr[kc], bfr, acc);
            }
            float bias_v = bias[ct * 16 + l15];
#pragma unroll
            for (int reg = 0; reg < 4; ++reg) {
                int nr = nrow + lg * 4 + reg;
                outm[(size_t)(b * N_ + nr) * C_ + ct * 16 + l15] = f2bf(acc[reg] + bias_v);
            }
        }
    }

    // ---- V: out[d][n], wave owns 64 d-rows ----
    int d0w = wav * 64;
#pragma unroll
    for (int dt = 0; dt < 4; ++dt) {
        const u16* awrow = wvb + (size_t)(d0w + dt * 16 + l15) * C_;
        bf16x8 av[8];
#pragma unroll
        for (int kc = 0; kc < 8; ++kc)
            av[kc] = *(const bf16x8*)(awrow + kc * 32 + lg * 8);
#pragma unroll
        for (int nt = 0; nt < 4; ++nt) {
            f32x4 acc = {0.f, 0.f, 0.f, 0.f};
            const u16* brow = poseT + (size_t)(b * N_ + n0 + nt * 16 + l15) * C_;
#pragma unroll
            for (int kc = 0; kc < 8; ++kc) {
                bf16x8 bfr = *(const bf16x8*)(brow + kc * 32 + lg * 8);
                acc = mfma16(av[kc], bfr, acc);
            }
#pragma unroll
            for (int reg = 0; reg < 4; ++reg) {
                int dd = d0w + dt * 16 + lg * 4 + reg;
                Vm[(size_t)(b * C_ + dd) * N_ + n0 + nt * 16 + l15] = f2bf(acc[reg] + bv[dd]);
            }
        }
    }
}

// ---------------- kernel 4: flash attention + residual ----------------
__global__ __launch_bounds__(256) void attn_kernel(
    const u16* __restrict__ Qm, const u16* __restrict__ Km, const u16* __restrict__ Vm,
    const float* __restrict__ pose, const float* __restrict__ gamma_p,
    float* __restrict__ out)
{
    __shared__ __align__(16) u16 Plds[4][16][72];
    __shared__ float Olds[64][65];

    int bid = blockIdx.x;              // 256
    // XCD swizzle: each batch pinned to 2 XCDs (K+V per batch = 4MB = L2)
    int xcd = bid & 7, pos = bid >> 3;
    int b = xcd >> 1;
    int i0 = ((xcd & 1) * 32 + pos) * 64;

    int lane = threadIdx.x & 63;
    int w = threadIdx.x >> 6;
    int l15 = lane & 15, lg = lane >> 4;

    const u16* qrow = Qm + (size_t)(b * N_ + i0 + w * 16 + l15) * C_;
    bf16x8 qf[8];
#pragma unroll
    for (int kc = 0; kc < 8; ++kc) qf[kc] = *(const bf16x8*)(qrow + kc * 32 + lg * 8);

    f32x4 Ot[16];
#pragma unroll
    for (int ct = 0; ct < 16; ++ct) Ot[ct] = (f32x4){0.f, 0.f, 0.f, 0.f};
    float m_r[4] = {-1e30f, -1e30f, -1e30f, -1e30f};
    float l_r[4] = {0.f, 0.f, 0.f, 0.f};

    const u16* Kb = Km + (size_t)b * N_ * C_;
    const u16* Vb = Vm + (size_t)b * C_ * N_;

    for (int jt = 0; jt < N_ / 64; ++jt) {
        int j0 = jt * 64;
        f32x4 s[4];
#pragma unroll
        for (int t = 0; t < 4; ++t) s[t] = (f32x4){0.f, 0.f, 0.f, 0.f};
#pragma unroll
        for (int t = 0; t < 4; ++t) {
            const u16* krow = Kb + (size_t)(j0 + t * 16 + l15) * C_;
#pragma unroll
            for (int kc = 0; kc < 8; ++kc) {
                bf16x8 kf = *(const bf16x8*)(krow + kc * 32 + lg * 8);
                s[t] = mfma16(qf[kc], kf, s[t]);
            }
        }
        // online softmax (rows: r = lg*4+reg, cols: t*16+l15)
        float scale_r[4];
#pragma unroll
        for (int reg = 0; reg < 4; ++reg) {
            float rm = fmaxf(fmaxf(s[0][reg], s[1][reg]), fmaxf(s[2][reg], s[3][reg]));
            rm = fmaxf(rm, __shfl_xor(rm, 1));
            rm = fmaxf(rm, __shfl_xor(rm, 2));
            rm = fmaxf(rm, __shfl_xor(rm, 4));
            rm = fmaxf(rm, __shfl_xor(rm, 8));
            float mn = fmaxf(m_r[reg], rm);
            scale_r[reg] = __expf(m_r[reg] - mn);
            m_r[reg] = mn;
            float rs = 0.f;
#pragma unroll
            for (int t = 0; t < 4; ++t) {
                float p = __expf(s[t][reg] - mn);
                s[t][reg] = p;
                rs += p;
            }
            rs += __shfl_xor(rs, 1);
            rs += __shfl_xor(rs, 2);
            rs += __shfl_xor(rs, 4);
            rs += __shfl_xor(rs, 8);
            l_r[reg] = l_r[reg] * scale_r[reg] + rs;
        }
#pragma unroll
        for (int ct = 0; ct < 16; ++ct)
#pragma unroll
            for (int reg = 0; reg < 4; ++reg)
                Ot[ct][reg] *= scale_r[reg];
        // P -> LDS (bf16), then re-read as A-fragments
#pragma unroll
        for (int t = 0; t < 4; ++t)
#pragma unroll
            for (int reg = 0; reg < 4; ++reg)
                Plds[w][lg * 4 + reg][t * 16 + l15] = f2bf(s[t][reg]);

        bf16x8 af[2];
#pragma unroll
        for (int ks = 0; ks < 2; ++ks)
            af[ks] = *(const bf16x8*)(&Plds[w][l15][ks * 32 + lg * 8]);
#pragma unroll
        for (int ct = 0; ct < 16; ++ct) {
            const u16* vrow = Vb + (size_t)(ct * 16 + l15) * N_ + j0;
#pragma unroll
            for (int ks = 0; ks < 2; ++ks) {
                bf16x8 vf = *(const bf16x8*)(vrow + ks * 32 + lg * 8);
                Ot[ct] = mfma16(af[ks], vf, Ot[ct]);
            }
        }
    }

    // epilogue: normalize, transpose through LDS, add residual, coalesced store
    float inv[4];
#pragma unroll
    for (int reg = 0; reg < 4; ++reg) inv[reg] = 1.0f / l_r[reg];
    float g = gamma_p[0];

    for (int cc = 0; cc < 4; ++cc) {
        __syncthreads();
#pragma unroll
        for (int u = 0; u < 4; ++u) {
            int ct = cc * 4 + u;
#pragma unroll
            for (int reg = 0; reg < 4; ++reg)
                Olds[w * 16 + lg * 4 + reg][u * 16 + l15] = Ot[ct][reg] * inv[reg];
        }
        __syncthreads();
#pragma unroll
        for (int r = 0; r < 16; ++r) {
            int cic = w * 16 + r;
            size_t addr = (size_t)(b * C_ + cc * 64 + cic) * N_ + i0 + lane;
            out[addr] = pose[addr] + g * Olds[lane][cic];
        }
    }
}

extern "C" void kernel_launch(void* const* d_in, const int* in_sizes, int n_in,
                              void* d_out, int out_size, void* d_ws, size_t ws_size,
                              hipStream_t stream) {
    (void)in_sizes; (void)n_in; (void)out_size; (void)ws_size;
    const float* pose = (const float*)d_in[0];
    const float* wq = (const float*)d_in[1];
    const float* bq = (const float*)d_in[2];
    const float* wk = (const float*)d_in[3];
    const float* bk = (const float*)d_in[4];
    const float* wv = (const float*)d_in[5];
    const float* bv = (const float*)d_in[6];
    const float* gamma = (const float*)d_in[7];
    float* out = (float*)d_out;

    char* ws = (char*)d_ws;
    u16* wqb   = (u16*)(ws + 0);
    u16* wkb   = (u16*)(ws + (128 << 10));
    u16* wvb   = (u16*)(ws + (256 << 10));
    u16* poseT = (u16*)(ws + (1 << 20));    // 8 MB
    u16* Qm    = (u16*)(ws + (9 << 20));    // 8 MB
    u16* Km    = (u16*)(ws + (17 << 20));   // 8 MB
    u16* Vm    = (u16*)(ws + (25 << 20));   // 8 MB

    hipLaunchKernelGGL(wconv_kernel, dim3(256), dim3(256), 0, stream, wq, wk, wv, wqb, wkb, wvb);
    hipLaunchKernelGGL(transpose_kernel, dim3(1024), dim3(256), 0, stream, pose, poseT);
    hipLaunchKernelGGL(proj_kernel, dim3(256), dim3(256), 0, stream,
                       poseT, wqb, bq, wkb, bk, wvb, bv, Qm, Km, Vm);
    hipLaunchKernelGGL(attn_kernel, dim3(256), dim3(256), 0, stream,
                       Qm, Km, Vm, pose, gamma, out);
}

// Round 2
// 566.870 us; speedup vs baseline: 1.2298x; 1.2298x over previous
//
#include <hip/hip_runtime.h>
#include <hip/hip_bf16.h>

#define B_ 4
#define C_ 256
#define N_ 4096

typedef unsigned short u16;
typedef __attribute__((ext_vector_type(8))) short bf16x8;
typedef __attribute__((ext_vector_type(4))) float f32x4;

static __device__ __forceinline__ u16 f2bf(float f) {
    unsigned u = __float_as_uint(f);
    unsigned r = (u + 0x7FFFu + ((u >> 16) & 1u)) >> 16;
    return (u16)r;
}
static __device__ __forceinline__ float bf2f(u16 u) {
    return __uint_as_float(((unsigned)u) << 16);
}

static __device__ __forceinline__ f32x4 mfma16(bf16x8 a, bf16x8 b, f32x4 c) {
    return __builtin_amdgcn_mfma_f32_16x16x32_bf16(a, b, c, 0, 0, 0);
}

// ---------------- kernel 1: weights f32 -> bf16 ----------------
__global__ void wconv_kernel(const float* __restrict__ wq, const float* __restrict__ wk,
                             const float* __restrict__ wv,
                             u16* __restrict__ wqb, u16* __restrict__ wkb, u16* __restrict__ wvb) {
    int i = blockIdx.x * blockDim.x + threadIdx.x;   // grid covers C_*C_
    wqb[i] = f2bf(wq[i]);
    wkb[i] = f2bf(wk[i]);
    wvb[i] = f2bf(wv[i]);
}

// ---------------- kernel 2: pose [B,C,N] f32 -> poseT [B,N,C] bf16 ----------------
__global__ void transpose_kernel(const float* __restrict__ pose, u16* __restrict__ poseT) {
    __shared__ float tile[64][65];
    int bid = blockIdx.x;              // B * 4 * 64 = 1024
    int b = bid >> 8;
    int rem = bid & 255;
    int ct = rem >> 6;                 // c-tile 0..3
    int nt = rem & 63;                 // n-tile 0..63
    int c0 = ct * 64, n0 = nt * 64;
    int tid = threadIdx.x;
    int lo = tid & 63, hi = tid >> 6;  // hi 0..3
#pragma unroll
    for (int r = 0; r < 16; ++r) {
        int cc = r * 4 + hi;
        tile[cc][lo] = pose[(size_t)(b * C_ + c0 + cc) * N_ + n0 + lo];
    }
    __syncthreads();
#pragma unroll
    for (int r = 0; r < 16; ++r) {
        int nn = r * 4 + hi;
        poseT[(size_t)(b * N_ + n0 + nn) * C_ + c0 + lo] = f2bf(tile[lo][nn]);
    }
}

// ---------------- kernel 3: projections ----------------
// Qm,Km: [B][N][C] bf16 ; Vm: [B][C][N] bf16
__global__ __launch_bounds__(256) void proj_kernel(
    const u16* __restrict__ poseT,
    const u16* __restrict__ wqb, const float* __restrict__ bq,
    const u16* __restrict__ wkb, const float* __restrict__ bk,
    const u16* __restrict__ wvb, const float* __restrict__ bv,
    u16* __restrict__ Qm, u16* __restrict__ Km, u16* __restrict__ Vm)
{
    int bid = blockIdx.x;              // B * N/64 = 256
    int b = bid >> 6;
    int n0 = (bid & 63) * 64;
    int lane = threadIdx.x & 63;
    int wav = threadIdx.x >> 6;        // 0..3
    int l15 = lane & 15, lg = lane >> 4;

    // ---- Q and K: out[n][d], wave owns 16 n-rows ----
    int nrow = n0 + wav * 16;
    const u16* arow = poseT + (size_t)(b * N_ + nrow + l15) * C_;
    bf16x8 afr[8];
#pragma unroll
    for (int kc = 0; kc < 8; ++kc)
        afr[kc] = *(const bf16x8*)(arow + kc * 32 + lg * 8);

    for (int qk = 0; qk < 2; ++qk) {
        const u16* wb = qk ? wkb : wqb;
        const float* bias = qk ? bk : bq;
        u16* outm = qk ? Km : Qm;
#pragma unroll
        for (int ct = 0; ct < 16; ++ct) {
            f32x4 acc = {0.f, 0.f, 0.f, 0.f};
            const u16* brow = wb + (size_t)(ct * 16 + l15) * C_;
#pragma unroll
            for (int kc = 0; kc < 8; ++kc) {
                bf16x8 bfr = *(const bf16x8*)(brow + kc * 32 + lg * 8);
                acc = mfma16(afr[kc], bfr, acc);
            }
            float bias_v = bias[ct * 16 + l15];
#pragma unroll
            for (int reg = 0; reg < 4; ++reg) {
                int nr = nrow + lg * 4 + reg;
                outm[(size_t)(b * N_ + nr) * C_ + ct * 16 + l15] = f2bf(acc[reg] + bias_v);
            }
        }
    }

    // ---- V: out[d][n], wave owns 64 d-rows ----
    int d0w = wav * 64;
#pragma unroll
    for (int dt = 0; dt < 4; ++dt) {
        const u16* awrow = wvb + (size_t)(d0w + dt * 16 + l15) * C_;
        bf16x8 av[8];
#pragma unroll
        for (int kc = 0; kc < 8; ++kc)
            av[kc] = *(const bf16x8*)(awrow + kc * 32 + lg * 8);
#pragma unroll
        for (int nt = 0; nt < 4; ++nt) {
            f32x4 acc = {0.f, 0.f, 0.f, 0.f};
            const u16* brow = poseT + (size_t)(b * N_ + n0 + nt * 16 + l15) * C_;
#pragma unroll
            for (int kc = 0; kc < 8; ++kc) {
                bf16x8 bfr = *(const bf16x8*)(brow + kc * 32 + lg * 8);
                acc = mfma16(av[kc], bfr, acc);
            }
#pragma unroll
            for (int reg = 0; reg < 4; ++reg) {
                int dd = d0w + dt * 16 + lg * 4 + reg;
                Vm[(size_t)(b * C_ + dd) * N_ + n0 + nt * 16 + l15] = f2bf(acc[reg] + bv[dd]);
            }
        }
    }
}

// ---------------- kernel 4: flash attention partial (j-split) ----------------
// pO[((s*B+b)*N + i)*C + c] bf16 unnormalized, pM/pL[(s*B+b)*N + i]
__global__ __launch_bounds__(256) void attn_partial_kernel(
    const u16* __restrict__ Qm, const u16* __restrict__ Km, const u16* __restrict__ Vm,
    u16* __restrict__ pO, float* __restrict__ pM, float* __restrict__ pL,
    int S, int jt_per_split)
{
    __shared__ __align__(16) u16 Plds[4][16][72];

    int G = 4 * S;
    int bid = blockIdx.x;              // 64 * G
    int pos = bid / G;                 // 0..63 : i-tile
    int g = bid % G;                   // blocks with same g share K/V slice (XCD-local)
    int b = g / S;
    int s = g % S;
    int i0 = pos * 64;

    int lane = threadIdx.x & 63;
    int w = threadIdx.x >> 6;
    int l15 = lane & 15, lg = lane >> 4;

    const u16* qrow = Qm + (size_t)(b * N_ + i0 + w * 16 + l15) * C_;
    bf16x8 qf[8];
#pragma unroll
    for (int kc = 0; kc < 8; ++kc) qf[kc] = *(const bf16x8*)(qrow + kc * 32 + lg * 8);

    f32x4 Ot[16];
#pragma unroll
    for (int ct = 0; ct < 16; ++ct) Ot[ct] = (f32x4){0.f, 0.f, 0.f, 0.f};
    float m_r[4] = {-1e30f, -1e30f, -1e30f, -1e30f};
    float l_r[4] = {0.f, 0.f, 0.f, 0.f};

    const u16* Kb = Km + (size_t)b * N_ * C_;
    const u16* Vb = Vm + (size_t)b * C_ * N_;

    int jt0 = s * jt_per_split;
    for (int jt = jt0; jt < jt0 + jt_per_split; ++jt) {
        int j0 = jt * 64;
        f32x4 sc[4];
#pragma unroll
        for (int t = 0; t < 4; ++t) sc[t] = (f32x4){0.f, 0.f, 0.f, 0.f};
#pragma unroll
        for (int t = 0; t < 4; ++t) {
            const u16* krow = Kb + (size_t)(j0 + t * 16 + l15) * C_;
#pragma unroll
            for (int kc = 0; kc < 8; ++kc) {
                bf16x8 kf = *(const bf16x8*)(krow + kc * 32 + lg * 8);
                sc[t] = mfma16(qf[kc], kf, sc[t]);
            }
        }
        // online softmax (rows: r = lg*4+reg, cols: t*16+l15)
        float scale_r[4];
#pragma unroll
        for (int reg = 0; reg < 4; ++reg) {
            float rm = fmaxf(fmaxf(sc[0][reg], sc[1][reg]), fmaxf(sc[2][reg], sc[3][reg]));
            rm = fmaxf(rm, __shfl_xor(rm, 1));
            rm = fmaxf(rm, __shfl_xor(rm, 2));
            rm = fmaxf(rm, __shfl_xor(rm, 4));
            rm = fmaxf(rm, __shfl_xor(rm, 8));
            float mn = fmaxf(m_r[reg], rm);
            scale_r[reg] = __expf(m_r[reg] - mn);
            m_r[reg] = mn;
            float rs = 0.f;
#pragma unroll
            for (int t = 0; t < 4; ++t) {
                float p = __expf(sc[t][reg] - mn);
                sc[t][reg] = p;
                rs += p;
            }
            rs += __shfl_xor(rs, 1);
            rs += __shfl_xor(rs, 2);
            rs += __shfl_xor(rs, 4);
            rs += __shfl_xor(rs, 8);
            l_r[reg] = l_r[reg] * scale_r[reg] + rs;
        }
#pragma unroll
        for (int ct = 0; ct < 16; ++ct)
#pragma unroll
            for (int reg = 0; reg < 4; ++reg)
                Ot[ct][reg] *= scale_r[reg];
        // P -> LDS (bf16), then re-read as A-fragments
#pragma unroll
        for (int t = 0; t < 4; ++t)
#pragma unroll
            for (int reg = 0; reg < 4; ++reg)
                Plds[w][lg * 4 + reg][t * 16 + l15] = f2bf(sc[t][reg]);

        bf16x8 af[2];
#pragma unroll
        for (int ks = 0; ks < 2; ++ks)
            af[ks] = *(const bf16x8*)(&Plds[w][l15][ks * 32 + lg * 8]);
#pragma unroll
        for (int ct = 0; ct < 16; ++ct) {
            const u16* vrow = Vb + (size_t)(ct * 16 + l15) * N_ + j0;
#pragma unroll
            for (int ks = 0; ks < 2; ++ks) {
                bf16x8 vf = *(const bf16x8*)(vrow + ks * 32 + lg * 8);
                Ot[ct] = mfma16(af[ks], vf, Ot[ct]);
            }
        }
    }

    // epilogue: write unnormalized partials + m,l
    size_t rowbase = (size_t)(s * B_ + b) * N_ + i0 + w * 16;
#pragma unroll
    for (int ct = 0; ct < 16; ++ct)
#pragma unroll
        for (int reg = 0; reg < 4; ++reg)
            pO[(rowbase + lg * 4 + reg) * C_ + ct * 16 + l15] = f2bf(Ot[ct][reg]);
    if (l15 == 0) {
#pragma unroll
        for (int reg = 0; reg < 4; ++reg) {
            size_t idx = rowbase + lg * 4 + reg;
            pM[idx] = m_r[reg];
            pL[idx] = l_r[reg];
        }
    }
}

// ---------------- kernel 5: combine partials + residual ----------------
__global__ __launch_bounds__(256) void combine_kernel(
    const u16* __restrict__ pO, const float* __restrict__ pM, const float* __restrict__ pL,
    const float* __restrict__ pose, const float* __restrict__ gamma_p,
    float* __restrict__ out, int S)
{
    __shared__ float a_s[4][64];
    __shared__ float tile[64][65];

    int bid = blockIdx.x;              // B*4*64 = 1024
    int b = bid >> 8;
    int ct = (bid >> 6) & 3;
    int it = bid & 63;
    int c0 = ct * 64, i0 = it * 64;
    int tid = threadIdx.x;

    if (tid < 64) {
        int i = i0 + tid;
        float M = -1e30f;
        for (int s = 0; s < S; ++s)
            M = fmaxf(M, pM[(size_t)(s * B_ + b) * N_ + i]);
        float L = 0.f;
        for (int s = 0; s < S; ++s) {
            size_t idx = (size_t)(s * B_ + b) * N_ + i;
            L += pL[idx] * __expf(pM[idx] - M);
        }
        float invL = 1.0f / L;
        for (int s = 0; s < S; ++s) {
            size_t idx = (size_t)(s * B_ + b) * N_ + i;
            a_s[s][tid] = __expf(pM[idx] - M) * invL;
        }
    }
    __syncthreads();

    int lane = tid & 63, hi = tid >> 6;
#pragma unroll
    for (int r = 0; r < 16; ++r) {
        int il = r * 4 + hi;
        float acc = 0.f;
        for (int s = 0; s < S; ++s) {
            u16 u = pO[((size_t)(s * B_ + b) * N_ + i0 + il) * C_ + c0 + lane];
            acc += a_s[s][il] * bf2f(u);
        }
        tile[il][lane] = acc;
    }
    __syncthreads();

    float g = gamma_p[0];
#pragma unroll
    for (int r = 0; r < 16; ++r) {
        int cc = r * 4 + hi;
        size_t addr = (size_t)(b * C_ + c0 + cc) * N_ + i0 + lane;
        out[addr] = pose[addr] + g * tile[lane][cc];
    }
}

extern "C" void kernel_launch(void* const* d_in, const int* in_sizes, int n_in,
                              void* d_out, int out_size, void* d_ws, size_t ws_size,
                              hipStream_t stream) {
    (void)in_sizes; (void)n_in; (void)out_size;
    const float* pose = (const float*)d_in[0];
    const float* wq = (const float*)d_in[1];
    const float* bq = (const float*)d_in[2];
    const float* wk = (const float*)d_in[3];
    const float* bk = (const float*)d_in[4];
    const float* wv = (const float*)d_in[5];
    const float* bv = (const float*)d_in[6];
    const float* gamma = (const float*)d_in[7];
    float* out = (float*)d_out;

    char* ws = (char*)d_ws;
    u16* wqb   = (u16*)(ws + 0);
    u16* wkb   = (u16*)(ws + (128 << 10));
    u16* wvb   = (u16*)(ws + (256 << 10));
    // pM/pL live in the [384K, 1M) gap (max 512 KB for S=4)
    u16* Qm    = (u16*)(ws + (1 << 20));     // 8 MB
    u16* Km    = (u16*)(ws + (9 << 20));     // 8 MB
    u16* Vm    = (u16*)(ws + (17 << 20));    // 8 MB
    u16* poseT = (u16*)(ws + (25 << 20));    // 8 MB (dead after proj)
    u16* pO    = (u16*)(ws + (25 << 20));    // S*8 MB, aliases poseT

    int S;
    if (ws_size >= ((size_t)57 << 20)) S = 4;
    else if (ws_size >= ((size_t)41 << 20)) S = 2;
    else S = 1;
    float* pM = (float*)(ws + (384 << 10));
    float* pL = pM + (size_t)S * B_ * N_;
    int jt_per_split = (N_ / 64) / S;

    hipLaunchKernelGGL(wconv_kernel, dim3(256), dim3(256), 0, stream, wq, wk, wv, wqb, wkb, wvb);
    hipLaunchKernelGGL(transpose_kernel, dim3(1024), dim3(256), 0, stream, pose, poseT);
    hipLaunchKernelGGL(proj_kernel, dim3(256), dim3(256), 0, stream,
                       poseT, wqb, bq, wkb, bk, wvb, bv, Qm, Km, Vm);
    hipLaunchKernelGGL(attn_partial_kernel, dim3(64 * 4 * S), dim3(256), 0, stream,
                       Qm, Km, Vm, pO, pM, pL, S, jt_per_split);
    hipLaunchKernelGGL(combine_kernel, dim3(1024), dim3(256), 0, stream,
                       pO, pM, pL, pose, gamma, out, S);
}